// Round 1
// baseline (397.969 us; speedup 1.0000x reference)
//
#include <hip/hip_runtime.h>
#include <stdint.h>

// Problem constants (fixed shapes)
#define BB 4
#define TT 4096
#define DD 1024
#define HH 1024
#define MM (BB * TT)      // 16384
#define NC 128            // scan chunks
#define CL (TT / NC)      // 32 steps per chunk

typedef __bf16 bf16x8 __attribute__((ext_vector_type(8)));
typedef float f32x4 __attribute__((ext_vector_type(4)));

// ---------------- helpers ----------------

__device__ __forceinline__ unsigned short f2bf(float f) {
    unsigned u = __float_as_uint(f);
    u += 0x7fffu + ((u >> 16) & 1u);   // round-to-nearest-even
    return (unsigned short)(u >> 16);
}

__device__ __forceinline__ float bf2f(unsigned short u) {
    return __uint_as_float(((unsigned)u) << 16);
}

__device__ __forceinline__ float softplusf(float x) {
    return (x > 15.f) ? x : log1pf(__expf(x));
}

__device__ __forceinline__ float g_fn(float x) {
    return (x >= 0.f) ? (x + 0.5f) : 1.0f / (1.0f + __expf(-x));
}

// async global->LDS, 16B per lane; hardware dest = wave-uniform base + lane*16
__device__ __forceinline__ void async_copy16(const void* gsrc, void* ldst) {
    __builtin_amdgcn_global_load_lds(
        reinterpret_cast<__attribute__((address_space(1))) unsigned int*>(
            reinterpret_cast<uintptr_t>(gsrc)),
        reinterpret_cast<__attribute__((address_space(3))) unsigned int*>(
            reinterpret_cast<uintptr_t>(ldst)),
        16, 0, 0);
}

// ---------------- fused cast kernel ----------------

__global__ void cast_all(const float* __restrict__ x,
                         const float* __restrict__ Wf,
                         const float* __restrict__ Wi,
                         const float* __restrict__ Wh,
                         unsigned short* __restrict__ xb,
                         unsigned short* __restrict__ Wb) {
    const int NX = MM * DD / 4;                 // 4194304 float4s of x
    int i = blockIdx.x * 256 + threadIdx.x;
    if (i < NX) {
        float4 v = reinterpret_cast<const float4*>(x)[i];
        ushort4 o;
        o.x = f2bf(v.x); o.y = f2bf(v.y); o.z = f2bf(v.z); o.w = f2bf(v.w);
        reinterpret_cast<ushort4*>(xb)[i] = o;
    } else {
        int j = i - NX;                         // 0 .. 786431
        if (j < 3 * 262144) {
            int which = j >> 18, k = j & 262143;
            const float* s = (which == 0) ? Wf : ((which == 1) ? Wi : Wh);
            float4 v = reinterpret_cast<const float4*>(s)[k];
            ushort4 o;
            o.x = f2bf(v.x); o.y = f2bf(v.y); o.z = f2bf(v.z); o.w = f2bf(v.w);
            reinterpret_cast<ushort4*>(Wb)[(which << 18) + k] = o;
        }
    }
}

// ---------------- fused 3-gate GEMM + gate math (v5) ----------------
// Block tile: 256(m) x 64(h) x 3 gates; 512 threads = 8 waves (4 pm x 2 ph),
// per-wave 64m x 32h x 3g -> acc[3][4][2] = 96 VGPRs.
// LDS 112 KiB: A = 4 sub-buffers of [256 rows][32 k] (16 KiB each, K=32
// granularity, depth-3 prefetch); B = 2 pair-buffers of [192 rows][64 k]
// (24 KiB each, K=64 granularity, depth-2 prefetch; B is L2-resident).
// All waits are counted vmcnt derived from the per-wave issue FIFO
// (A: 2 issues/subtile every step; B: 3 issues/pair every even step):
//   even step t: need A(t)+B(p);  newer ops = A(t+2)x2 A(t+3)x2 B(p+1)x3 -> vmcnt(7)
//   odd  step t: need A(t)+B(p);  newer ops = A(t+1)x2 A(t+2)x2 B(p+1)x3 A(t+3)x2 -> vmcnt(9)
// setprio(1) around the MFMA cluster (T5: phase-split schedule present).
// Swizzles: A rows are 64 B, 4x16B chunks, store/read chunk c = q ^ (r&3)
// (8 lanes per 16B column -> conflict-free). B rows are 128 B, 8-chunk XOR
// c = q ^ (r&7) -- byte-identical to the previous (verified) kernel.

#define ISSUE_A(AB) do {                                                      \
    async_copy16(gA0, smem + (AB) * 16384 + aoff0); gA0 += 32;                \
    async_copy16(gA1, smem + (AB) * 16384 + aoff1); gA1 += 32;                \
} while (0)

#define ISSUE_B(BBF) do {                                                     \
    async_copy16(gB0, smem + 65536 + (BBF) * 24576 + boff0); gB0 += 64;       \
    async_copy16(gB1, smem + 65536 + (BBF) * 24576 + boff1); gB1 += 64;       \
    async_copy16(gB2, smem + 65536 + (BBF) * 24576 + boff2); gB2 += 64;       \
} while (0)

#define COMPUTE(AB, BBF, BRD) do {                                            \
    const char* Ab = smem + (AB) * 16384;                                     \
    const char* Bb = smem + 65536 + (BBF) * 24576;                            \
    bf16x8 af[4];                                                             \
    _Pragma("unroll")                                                         \
    for (int mt = 0; mt < 4; ++mt)                                            \
        af[mt] = *reinterpret_cast<const bf16x8*>(Ab + a_rd + mt * 1024);     \
    bf16x8 bfr[3][2];                                                         \
    _Pragma("unroll")                                                         \
    for (int g = 0; g < 3; ++g)                                               \
        _Pragma("unroll")                                                     \
        for (int nt = 0; nt < 2; ++nt)                                        \
            bfr[g][nt] = *reinterpret_cast<const bf16x8*>(                    \
                Bb + (BRD) + g * 8192 + nt * 2048);                           \
    __builtin_amdgcn_s_setprio(1);                                            \
    _Pragma("unroll")                                                         \
    for (int g = 0; g < 3; ++g)                                               \
        _Pragma("unroll")                                                     \
        for (int mt = 0; mt < 4; ++mt)                                        \
            _Pragma("unroll")                                                 \
            for (int nt = 0; nt < 2; ++nt)                                    \
                acc[g][mt][nt] = __builtin_amdgcn_mfma_f32_16x16x32_bf16(     \
                    af[mt], bfr[g][nt], acc[g][mt][nt], 0, 0, 0);             \
    __builtin_amdgcn_s_setprio(0);                                            \
} while (0)

#define STEP_E(CA, IA, CB, IB) do {                                           \
    ISSUE_A(IA);                                                              \
    ISSUE_B(IB);                                                              \
    asm volatile("s_waitcnt vmcnt(7)" ::: "memory");                          \
    __builtin_amdgcn_s_barrier();                                             \
    COMPUTE(CA, CB, b_rd0);                                                   \
    asm volatile("s_waitcnt lgkmcnt(0)" ::: "memory");                        \
    __builtin_amdgcn_s_barrier();                                             \
} while (0)

#define STEP_O(CA, IA, CB) do {                                               \
    ISSUE_A(IA);                                                              \
    asm volatile("s_waitcnt vmcnt(9)" ::: "memory");                          \
    __builtin_amdgcn_s_barrier();                                             \
    COMPUTE(CA, CB, b_rd1);                                                   \
    asm volatile("s_waitcnt lgkmcnt(0)" ::: "memory");                        \
    __builtin_amdgcn_s_barrier();                                             \
} while (0)

__global__ __launch_bounds__(512, 2) void gemm_gates(
    const unsigned short* __restrict__ xb,
    const unsigned short* __restrict__ Wb,
    const float* __restrict__ bf_p, const float* __restrict__ bi_p,
    const float* __restrict__ bh_p,
    unsigned short* __restrict__ F, unsigned short* __restrict__ V) {
    __shared__ char smem[114688];   // A: 4 x 16 KiB | B: 2 x 24 KiB

    const int tid  = threadIdx.x;
    const int wave = tid >> 6;      // 0..7
    const int lane = tid & 63;

    // XCD swizzle (bijective over 1024 blocks): blocks sharing bm AND blocks
    // sharing bh land on one XCD -> both the 384 KB B slice and the A m-slice
    // stay L2-resident per XCD.
    const int bidx = blockIdx.x;          // 0..1023
    const int xcd  = bidx & 7;
    const int jj   = bidx >> 3;           // 0..127
    const int bm   = ((jj & 7) << 3) | xcd;   // [0,64)
    const int bh   = jj >> 3;                 // [0,16)

    const int pm = wave >> 1;       // 0..3 : 64-row m patch
    const int ph = wave & 1;        // 0..1 : 32-col h patch

    // ---- staging pointers ----
    // A: per wave rows [wave*32, wave*32+32), 2 issues of 16 rows.
    // lane -> local row lr = lane>>2, chunk q = lane&3; global chunk = q^(lr&3).
    const int lrA = lane >> 2;                       // 0..15
    const int qA  = (lane & 3) ^ (lrA & 3);          // swizzled 16B chunk
    const unsigned short* gA0 = xb +
        (size_t)(bm * 256 + wave * 32 + 0 * 16 + lrA) * DD + qA * 8;
    const unsigned short* gA1 = xb +
        (size_t)(bm * 256 + wave * 32 + 1 * 16 + lrA) * DD + qA * 8;
    const int aoff0 = wave * 2048;
    const int aoff1 = wave * 2048 + 1024;

    // B: per wave rows [wave*24, wave*24+24) of 192 (= 3 gates x 64 h),
    // 3 issues of 8 rows. lane -> lr8 = lane>>3, chunk q8 = lane&7;
    // global chunk = q8 ^ lr8. Row blocks never straddle a gate boundary.
    const int lr8 = lane >> 3;                       // 0..7
    const int q8  = (lane & 7) ^ lr8;
    const unsigned short* gB0;
    const unsigned short* gB1;
    const unsigned short* gB2;
    {
        int rb0 = wave * 24 + 0 * 8, rb1 = wave * 24 + 1 * 8, rb2 = wave * 24 + 2 * 8;
        gB0 = Wb + (size_t)(rb0 >> 6) * 1048576 +
              (size_t)(bh * 64 + (rb0 & 63) + lr8) * DD + q8 * 8;
        gB1 = Wb + (size_t)(rb1 >> 6) * 1048576 +
              (size_t)(bh * 64 + (rb1 & 63) + lr8) * DD + q8 * 8;
        gB2 = Wb + (size_t)(rb2 >> 6) * 1048576 +
              (size_t)(bh * 64 + (rb2 & 63) + lr8) * DD + q8 * 8;
    }
    const int boff0 = wave * 3072;
    const int boff1 = wave * 3072 + 1024;
    const int boff2 = wave * 3072 + 2048;

    // ---- compute-side lane constants (byte offsets) ----
    // A rows 64 B: read chunk (lane>>4) ^ (row&3), row&3 == lane&3.
    const int a_rd  = (pm * 64 + (lane & 15)) * 64 +
                      (((lane >> 4) ^ (lane & 3)) << 4);
    // B rows 128 B: read chunk (kh*4 + (lane>>4)) ^ (row&7), row&7 == lane&7.
    const int b_rd0 = (ph * 32 + (lane & 15)) * 128 +
                      ((((lane >> 4) + 0) ^ (lane & 7)) << 4);
    const int b_rd1 = (ph * 32 + (lane & 15)) * 128 +
                      ((((lane >> 4) + 4) ^ (lane & 7)) << 4);

    f32x4 acc[3][4][2];
#pragma unroll
    for (int g = 0; g < 3; ++g)
#pragma unroll
        for (int mt = 0; mt < 4; ++mt)
#pragma unroll
            for (int nt = 0; nt < 2; ++nt)
                acc[g][mt][nt] = (f32x4){0.f, 0.f, 0.f, 0.f};

    // ---- prologue (order matters for the vmcnt FIFO accounting) ----
    ISSUE_A(0);         // A subtile 0 -> buf 0
    ISSUE_A(1);         // A subtile 1 -> buf 1
    ISSUE_B(0);         // B pair 0    -> bbuf 0
    ISSUE_A(2);         // A subtile 2 -> buf 2

    // ---- main loop: subtiles 0..27, period-4 schedule ----
    for (int it = 0; it < 7; ++it) {
        STEP_E(0, 3, 0, 1);   // t=4it+0: A buf0, issue A->3, B bbuf0/h0, issue B->1
        STEP_O(1, 0, 0);      // t=4it+1: A buf1, issue A->0, B bbuf0/h1
        STEP_E(2, 1, 1, 0);   // t=4it+2: A buf2, issue A->1, B bbuf1/h0, issue B->0
        STEP_O(3, 2, 1);      // t=4it+3: A buf3, issue A->2, B bbuf1/h1
    }

    // ---- tail: subtiles 28..31 ----
    STEP_E(0, 3, 0, 1);       // t=28 (last full-issue step: A31, B pair15)
    COMPUTE(1, 0, b_rd1);     // t=29 (A29/B14 completed at t=28's vmcnt(7))
    asm volatile("s_waitcnt vmcnt(0)" ::: "memory");
    __builtin_amdgcn_s_barrier();
    COMPUTE(2, 1, b_rd0);     // t=30
    COMPUTE(3, 1, b_rd1);     // t=31

    // ---- epilogue: bias + normalized gates, write f and v (bf16) ----
    const int m0  = bm * 256 + pm * 64 + (lane >> 4) * 4;
    const int h0i = bh * 64 + ph * 32 + (lane & 15);
#pragma unroll
    for (int nt = 0; nt < 2; ++nt) {
        const int h = h0i + nt * 16;
        const float bfs = bf_p[h], bis = bi_p[h], bhs = bh_p[h];
#pragma unroll
        for (int mt = 0; mt < 4; ++mt) {
#pragma unroll
            for (int r = 0; r < 4; ++r) {
                const int m = m0 + mt * 16 + r;
                float zf = acc[0][mt][nt][r] + bfs;
                float zi = acc[1][mt][nt][r] + bis;
                float zh = acc[2][mt][nt][r] + bhs;
                float d  = softplusf(-zf) - softplusf(-zi);
                float f  = 1.0f / (1.0f + __expf(d));   // sigmoid(-d)
                float iv = 1.0f - f;                    // sigmoid(d)
                float gg = g_fn(zh);
                size_t o = (size_t)m * HH + h;
                F[o] = f2bf(f);
                V[o] = f2bf(iv * gg);
            }
        }
    }
}

// ---------------- scan (3-pass chunked linear scan) ----------------
// h_t = f_t*h_{t-1} + v_t ; f+i=1 convex combination -> stable in fp32.
// F/V in bf16, summaries and output fp32.

__global__ void scan1_kernel(const unsigned short* __restrict__ F,
                             const unsigned short* __restrict__ V,
                             float* __restrict__ Fc, float* __restrict__ Vc) {
    const int bx = blockIdx.x, tid = threadIdx.x;
    const int c = bx & (NC - 1), b = bx >> 7;
    const ushort4* F4 = (const ushort4*)F;
    const ushort4* V4 = (const ushort4*)V;
    size_t base = ((size_t)(b * TT + c * CL) * HH) / 4 + tid;
    float4 Fp = {1.f, 1.f, 1.f, 1.f}, hv = {0.f, 0.f, 0.f, 0.f};
#pragma unroll 8
    for (int s = 0; s < CL; ++s) {
        ushort4 fu = F4[base + (size_t)s * (HH / 4)];
        ushort4 vu = V4[base + (size_t)s * (HH / 4)];
        hv.x = fmaf(bf2f(fu.x), hv.x, bf2f(vu.x)); Fp.x *= bf2f(fu.x);
        hv.y = fmaf(bf2f(fu.y), hv.y, bf2f(vu.y)); Fp.y *= bf2f(fu.y);
        hv.z = fmaf(bf2f(fu.z), hv.z, bf2f(vu.z)); Fp.z *= bf2f(fu.z);
        hv.w = fmaf(bf2f(fu.w), hv.w, bf2f(vu.w)); Fp.w *= bf2f(fu.w);
    }
    size_t ci = ((size_t)(b * NC + c) * HH) / 4 + tid;
    ((float4*)Fc)[ci] = Fp;
    ((float4*)Vc)[ci] = hv;
}

__global__ void scan2_kernel(const float* __restrict__ h0,
                             const float* __restrict__ Fc,
                             const float* __restrict__ Vc,
                             float* __restrict__ Hin) {
    const int gid = blockIdx.x * 256 + threadIdx.x;   // 0..4095
    const int b = gid >> 10, h = gid & (HH - 1);
    float carry = g_fn(h0[gid]);
#pragma unroll 8
    for (int c = 0; c < NC; ++c) {
        int ci = (b * NC + c) * HH + h;
        Hin[ci] = carry;
        carry = fmaf(Fc[ci], carry, Vc[ci]);
    }
}

__global__ void scan3_kernel(const unsigned short* __restrict__ F,
                             const unsigned short* __restrict__ V,
                             const float* __restrict__ Hin,
                             float* __restrict__ Out) {
    const int bx = blockIdx.x, tid = threadIdx.x;
    const int c = bx & (NC - 1), b = bx >> 7;
    const ushort4* F4 = (const ushort4*)F;
    const ushort4* V4 = (const ushort4*)V;
    float4* O4 = (float4*)Out;
    size_t base = ((size_t)(b * TT + c * CL) * HH) / 4 + tid;
    size_t ci = ((size_t)(b * NC + c) * HH) / 4 + tid;
    float4 carry = ((const float4*)Hin)[ci];
#pragma unroll 8
    for (int s = 0; s < CL; ++s) {
        size_t idx = base + (size_t)s * (HH / 4);
        ushort4 fu = F4[idx];
        ushort4 vu = V4[idx];
        carry.x = fmaf(bf2f(fu.x), carry.x, bf2f(vu.x));
        carry.y = fmaf(bf2f(fu.y), carry.y, bf2f(vu.y));
        carry.z = fmaf(bf2f(fu.z), carry.z, bf2f(vu.z));
        carry.w = fmaf(bf2f(fu.w), carry.w, bf2f(vu.w));
        O4[idx] = carry;
    }
}

// ---------------- launch ----------------

extern "C" void kernel_launch(void* const* d_in, const int* in_sizes, int n_in,
                              void* d_out, int out_size, void* d_ws, size_t ws_size,
                              hipStream_t stream) {
    const float* x   = (const float*)d_in[0];
    const float* h0  = (const float*)d_in[1];
    const float* Wf  = (const float*)d_in[2];
    const float* bfp = (const float*)d_in[3];
    const float* Wi  = (const float*)d_in[4];
    const float* bip = (const float*)d_in[5];
    const float* Wh  = (const float*)d_in[6];
    const float* bhp = (const float*)d_in[7];
    float* out = (float*)d_out;

    char* ws = (char*)d_ws;
    unsigned short* xb = (unsigned short*)ws;                   // 32 MiB bf16 x
    unsigned short* Wb = (unsigned short*)(ws + 33554432);      // 6 MiB bf16 W
    unsigned short* Fb = (unsigned short*)(ws + 39845888);      // 32 MiB bf16 f
    unsigned short* Vb = (unsigned short*)(ws + 73400320);      // 32 MiB bf16 v
    float* Fc  = (float*)(ws);                                  // 2 MiB (aliases xb)
    float* Vc  = (float*)(ws + 2097152);                        // 2 MiB
    float* Hin = (float*)(ws + 4194304);                        // 2 MiB

    cast_all<<<19456, 256, 0, stream>>>(x, Wf, Wi, Wh, xb, Wb);
    gemm_gates<<<1024, 512, 0, stream>>>(xb, Wb, bfp, bip, bhp, Fb, Vb);
    scan1_kernel<<<BB * NC, 256, 0, stream>>>(Fb, Vb, Fc, Vc);
    scan2_kernel<<<16, 256, 0, stream>>>(h0, Fc, Vc, Hin);
    scan3_kernel<<<BB * NC, 256, 0, stream>>>(Fb, Vb, Hin, out);
}